// Round 3
// baseline (483.321 us; speedup 1.0000x reference)
//
#include <hip/hip_runtime.h>

typedef unsigned short u16;
typedef __attribute__((ext_vector_type(8))) short bf16x8;
typedef __attribute__((ext_vector_type(4))) float f32x4;

__device__ inline float bf2f(u16 h) {
    union { unsigned u; float f; } v; v.u = ((unsigned)h) << 16; return v.f;
}
__device__ inline u16 f2bf(float f) {
    union { float f; unsigned u; } v; v.f = f;
    unsigned r = v.u + 0x7fffu + ((v.u >> 16) & 1u);
    return (u16)(r >> 16);
}

__device__ inline void gl_lds16(const u16* g, u16* l) {
    __builtin_amdgcn_global_load_lds(
        (const __attribute__((address_space(1))) void*)g,
        (__attribute__((address_space(3))) void*)l, 16, 0, 0);
}

__device__ __forceinline__ void wgbar() {
    asm volatile("" ::: "memory");
    __builtin_amdgcn_s_barrier();
    asm volatile("" ::: "memory");
}
#define VMW(n) asm volatile("s_waitcnt vmcnt(" #n ")" ::: "memory")

// ---------------------------------------------------------------------------
// f32 -> bf16 elementwise convert, up to 4 arrays per launch.
// ---------------------------------------------------------------------------
__global__ __launch_bounds__(256) void cvt_bf16_k(
    const float* __restrict__ s0, u16* __restrict__ d0, long long n0,
    const float* __restrict__ s1, u16* __restrict__ d1, long long n1,
    const float* __restrict__ s2, u16* __restrict__ d2, long long n2,
    const float* __restrict__ s3, u16* __restrict__ d3, long long n3)
{
    int y = blockIdx.y;
    const float* s = (y == 0) ? s0 : (y == 1) ? s1 : (y == 2) ? s2 : s3;
    u16* d         = (y == 0) ? d0 : (y == 1) ? d1 : (y == 2) ? d2 : d3;
    long long n    = (y == 0) ? n0 : (y == 1) ? n1 : (y == 2) ? n2 : n3;
    for (long long i = (long long)blockIdx.x * 256 + threadIdx.x; i < n;
         i += (long long)gridDim.x * 256) {
        float4 v = ((const float4*)s)[i];
        union { u16 h[4]; unsigned long long u; } p;
        p.h[0] = f2bf(v.x); p.h[1] = f2bf(v.y);
        p.h[2] = f2bf(v.z); p.h[3] = f2bf(v.w);
        ((unsigned long long*)d)[i] = p.u;
    }
}

// ---------------------------------------------------------------------------
// 8-phase 256x256 GEMM (T2+T3+T4+T5 per the 8-phase template):
//   C[M,N] = (A[M,K] @ Bt[N,K]^T) * scale + bias
// 512 thr = 8 waves (2M x 4N), BK=64, 2 K-tiles per main iter, 8 phases/iter.
// LDS 128 KiB: A/B x 2 slots x 2 halves x [128][64] bf16, XOR-swizzled
// (elem ^= (row&7)<<3) with inverse-swizzled global source (rule 21).
// Counted vmcnt(2) at phases 4/8 only; vmcnt(0) on final iter.
// NSPLIT: output cols split into 1024-wide segments -> C0/C1/C2, bias0/1/2.
// BIASROW: bias indexed by output row (for W @ x^T style GEMMs).
// ldb = Bt row stride; bofs_stride: B element offset += (bm0>>11)*bofs_stride
// (per-batch K-offset for PV reading VtAll[1024][8192]).
// ---------------------------------------------------------------------------
#define STA(T, H)                                                             \
    { const u16* g_ = Ag + (long long)((H) * 128 + w * 8 + srow) * K          \
                      + (T) * 64 + scol;                                      \
      u16* l_ = (u16*)&As[(T) & 1][H][w * 512];                               \
      gl_lds16(g_, l_);                                                       \
      gl_lds16(g_ + (long long)64 * K, l_ + 4096); }

#define STB(T, H)                                                             \
    { const u16* g_ = Bg + (long long)(bn0 + (H) * 128 + w * 8 + srow) * ldb  \
                      + (T) * 64 + scol;                                      \
      u16* l_ = (u16*)&Bs[(T) & 1][H][w * 512];                               \
      gl_lds16(g_, l_);                                                       \
      gl_lds16(g_ + (long long)64 * ldb, l_ + 4096); }

#define G8_PHASE(T, MQ, NQ, STAGES, WAITS)                                    \
    {                                                                         \
        bf16x8 av[4][2], bvv[2][2];                                           \
        _Pragma("unroll")                                                     \
        for (int ii = 0; ii < 4; ii++) {                                      \
            int row = (MQ) * 64 + ii * 16 + lane15;                           \
            _Pragma("unroll")                                                 \
            for (int ks = 0; ks < 2; ks++)                                    \
                av[ii][ks] = *(const bf16x8*)&As[(T) & 1][wm2]                \
                    [(row * 64 + ks * 32 + quad * 8) ^ xr];                   \
        }                                                                     \
        _Pragma("unroll")                                                     \
        for (int jj = 0; jj < 2; jj++) {                                      \
            int row = (wn2 & 1) * 64 + (NQ) * 32 + jj * 16 + lane15;          \
            _Pragma("unroll")                                                 \
            for (int ks = 0; ks < 2; ks++)                                    \
                bvv[jj][ks] = *(const bf16x8*)&Bs[(T) & 1][wn2 >> 1]          \
                    [(row * 64 + ks * 32 + quad * 8) ^ xr];                   \
        }                                                                     \
        STAGES;                                                               \
        WAITS;                                                                \
        wgbar();                                                              \
        __builtin_amdgcn_s_setprio(1);                                        \
        _Pragma("unroll")                                                     \
        for (int ii = 0; ii < 4; ii++)                                        \
            _Pragma("unroll")                                                 \
            for (int jj = 0; jj < 2; jj++) {                                  \
                acc[(MQ)*4+ii][(NQ)*2+jj] =                                   \
                    __builtin_amdgcn_mfma_f32_16x16x32_bf16(                  \
                        av[ii][0], bvv[jj][0], acc[(MQ)*4+ii][(NQ)*2+jj],     \
                        0, 0, 0);                                             \
                acc[(MQ)*4+ii][(NQ)*2+jj] =                                   \
                    __builtin_amdgcn_mfma_f32_16x16x32_bf16(                  \
                        av[ii][1], bvv[jj][1], acc[(MQ)*4+ii][(NQ)*2+jj],     \
                        0, 0, 0);                                             \
            }                                                                 \
        __builtin_amdgcn_s_setprio(0);                                        \
        wgbar();                                                              \
    }

template <int COUTF32, int BIASROW, int NSPLIT>
__global__ __launch_bounds__(512, 2) void gemm8(
    const u16* __restrict__ A, const u16* __restrict__ Bt,
    const float* __restrict__ bias0, const float* __restrict__ bias1,
    const float* __restrict__ bias2,
    void* __restrict__ C0, void* __restrict__ C1, void* __restrict__ C2,
    int M, int N, int K, int ldb, float scale,
    long long sAb, long long sBb, long long sCb, long long bofs_stride)
{
    __shared__ u16 As[2][2][8192];
    __shared__ u16 Bs[2][2][8192];

    int b   = blockIdx.z;
    int bm0 = blockIdx.x * 256;
    int bn0 = blockIdx.y * 256;
    int tid = threadIdx.x;
    int w = tid >> 6, l = tid & 63;
    int wm2 = w >> 2;            // M half (0..1): wave's 128 output rows
    int wn2 = w & 3;             // N quarter (0..3): wave's 64 output cols
    int lane15 = l & 15, quad = l >> 4;
    int xr = (l & 7) << 3;       // read-side swizzle (elems)

    // staging lane geometry: 8 thr/row, inverse-swizzled source column
    int srow = l >> 3;
    int scol = ((l & 7) ^ (srow & 7)) * 8;

    const u16* Ag = A  + (long long)b * sAb + (long long)bm0 * K;
    const u16* Bg = Bt + (long long)b * sBb + (long long)(bm0 >> 11) * bofs_stride;

    f32x4 acc[8][4];
#pragma unroll
    for (int i = 0; i < 8; i++)
#pragma unroll
        for (int j = 0; j < 4; j++) acc[i][j] = (f32x4)(0.0f);

    int NT  = K >> 6;   // 64-wide K tiles
    int NT2 = K >> 7;   // main iters (2 tiles each)

    // Prologue: tile0 (4 halves) + A-M1(tile1); confirm tile0, leave 1 in flight
    STA(0, 0); STA(0, 1); STB(0, 0); STB(0, 1); STA(1, 1);
    VMW(2);
    wgbar();

    for (int j = 0; j < NT2; ++j) {
        int t0 = 2 * j, t1 = 2 * j + 1;
        bool nl = (j < NT2 - 1);
        // tile t0 (even): quadrants (M0,N0),(M0,N1),(M1,N1),(M1,N0)
        G8_PHASE(t0, 0, 0, STA(t1, 0), );
        G8_PHASE(t0, 0, 1, STB(t1, 0), );
        G8_PHASE(t0, 1, 1, STB(t1, 1), );
        G8_PHASE(t0, 1, 0, if (nl) STA(t0 + 2, 0),
                 if (nl) { VMW(2); } else { VMW(0); });
        // tile t1 (odd): quadrants (M1,N0),(M1,N1),(M0,N1),(M0,N0)
        G8_PHASE(t1, 1, 0, if (nl) STA(t0 + 2, 1), );
        G8_PHASE(t1, 1, 1, if (nl) STB(t0 + 2, 0), );
        G8_PHASE(t1, 0, 1, if (nl) STB(t0 + 2, 1), );
        G8_PHASE(t1, 0, 0, if (nl) STA(t0 + 3, 1),
                 if (nl) { VMW(2); } else { VMW(0); });
    }

    // Epilogue: C/D layout col=lane15 (within frag j), row=quad*4+r (frag i)
    float rowb_[8][4];
    if (BIASROW) {
#pragma unroll
        for (int i = 0; i < 8; i++)
#pragma unroll
            for (int r = 0; r < 4; r++)
                rowb_[i][r] = bias0[bm0 + wm2 * 128 + i * 16 + quad * 4 + r];
    }
#pragma unroll
    for (int jj = 0; jj < 4; jj++) {
        int col = bn0 + wn2 * 64 + jj * 16 + lane15;
        int seg, cl, cstride;
        if (NSPLIT == 1) { seg = 0; cl = col; cstride = N; }
        else             { seg = col >> 10; cl = col & 1023; cstride = 1024; }
        const float* bp = (seg == 0) ? bias0 : (seg == 1 ? bias1 : bias2);
        void* cb = (seg == 0) ? C0 : (seg == 1 ? C1 : C2);
        u16*   c16 = (u16*)cb   + (long long)b * sCb;
        float* c32 = (float*)cb + (long long)b * sCb;
        float bvc = (!BIASROW && bp) ? bp[cl] : 0.0f;
#pragma unroll
        for (int i = 0; i < 8; i++) {
            int row0 = bm0 + wm2 * 128 + i * 16 + quad * 4;
#pragma unroll
            for (int r = 0; r < 4; r++) {
                float v = acc[i][jj][r] * scale + (BIASROW ? rowb_[i][r] : bvc);
                if (COUTF32) c32[(long long)(row0 + r) * cstride + cl] = v;
                else         c16[(long long)(row0 + r) * cstride + cl] = f2bf(v);
            }
        }
    }
}

// ---------------------------------------------------------------------------
// Row softmax in-place: 8192 rows of 2048 bf16
// ---------------------------------------------------------------------------
__global__ __launch_bounds__(256) void softmax_k(u16* __restrict__ Sc)
{
    long long row = blockIdx.x;
    u16* s = Sc + row * 2048;
    int t = threadIdx.x;

    uint4 raw = *(const uint4*)(s + t * 8);
    const u16* rp = (const u16*)&raw;
    float v[8];
    float mx = -3.4e38f;
#pragma unroll
    for (int j = 0; j < 8; j++) { v[j] = bf2f(rp[j]); mx = fmaxf(mx, v[j]); }
#pragma unroll
    for (int o = 32; o > 0; o >>= 1) mx = fmaxf(mx, __shfl_xor(mx, o));
    __shared__ float redm[4];
    if ((t & 63) == 0) redm[t >> 6] = mx;
    __syncthreads();
    mx = fmaxf(fmaxf(redm[0], redm[1]), fmaxf(redm[2], redm[3]));

    float sum = 0.0f;
#pragma unroll
    for (int j = 0; j < 8; j++) { v[j] = __expf(v[j] - mx); sum += v[j]; }
#pragma unroll
    for (int o = 32; o > 0; o >>= 1) sum += __shfl_xor(sum, o);
    __shared__ float reds[4];
    if ((t & 63) == 0) reds[t >> 6] = sum;
    __syncthreads();
    sum = reds[0] + reds[1] + reds[2] + reds[3];

    float inv = 1.0f / sum;
    u16 o8[8];
#pragma unroll
    for (int j = 0; j < 8; j++) o8[j] = f2bf(v[j] * inv);
    *(uint4*)(s + t * 8) = *(const uint4*)o8;
}

// ---------------------------------------------------------------------------
// Gate partial: grid (B, 128). Each block: 16 rows of h[b], bf16x8 loads.
// ---------------------------------------------------------------------------
__global__ __launch_bounds__(256) void gate_partial(const u16* __restrict__ h,
                                                    const float* __restrict__ Wg,
                                                    float* __restrict__ part)
{
    int b = blockIdx.x, c = blockIdx.y;
    int t = threadIdx.x;
    int tx = t & 127;
    int ty = t >> 7;
    int d0 = tx * 8;
    const u16* hb = h + (long long)b * 2048 * 1024 + (long long)c * 16 * 1024;

    float wg[8];
#pragma unroll
    for (int j = 0; j < 8; j++) wg[j] = Wg[d0 + j];

    float acc = 0.0f;
    for (int s = ty; s < 16; s += 2) {
        bf16x8 hv = *(const bf16x8*)&hb[(long long)s * 1024 + d0];
        const u16* hp = (const u16*)&hv;
#pragma unroll
        for (int j = 0; j < 8; j++) acc += bf2f(hp[j]) * wg[j];
    }
#pragma unroll
    for (int o = 32; o > 0; o >>= 1) acc += __shfl_xor(acc, o);
    __shared__ float red[4];
    if ((t & 63) == 0) red[t >> 6] = acc;
    __syncthreads();
    if (t == 0) part[b * 128 + c] = red[0] + red[1] + red[2] + red[3];
}

__global__ void gate_final(const float* __restrict__ part,
                           const float* __restrict__ bg, float* __restrict__ outp)
{
    int t = threadIdx.x;
    if (t < 4) {
        float s = 0.0f;
        for (int c = 0; c < 128; c++) s += part[t * 128 + c];
        float v = s * (1.0f / 2048.0f) + bg[0];
        outp[t] = 1.0f / (1.0f + __expf(-v));
    }
}

// ---------------------------------------------------------------------------
// Epilogue: z = relu(mu + eps*exp(0.5*logvar)); out = LN(x+z)*gamma+beta
// ---------------------------------------------------------------------------
__global__ __launch_bounds__(256) void epilogue_k(
    const float* __restrict__ x, const float* __restrict__ ep,
    const float* __restrict__ mu, const float* __restrict__ lv,
    const float* __restrict__ gamma, const float* __restrict__ beta,
    float* __restrict__ out)
{
    long long base = (long long)blockIdx.x * 1024;
    int t = threadIdx.x;
    float y[4];
    float sum = 0.0f, sq = 0.0f;
#pragma unroll
    for (int j = 0; j < 4; j++) {
        int i = j * 256 + t;
        float xv = x[base + i];
        float ev = ep[base + i];
        float m  = mu[base + i];
        float sd = __expf(0.5f * lv[base + i]);
        float z  = fmaxf(m + ev * sd, 0.0f);
        float yy = xv + z;
        y[j] = yy; sum += yy; sq += yy * yy;
    }
#pragma unroll
    for (int o = 32; o > 0; o >>= 1) { sum += __shfl_xor(sum, o); sq += __shfl_xor(sq, o); }
    __shared__ float rs[4], rq[4];
    if ((t & 63) == 0) { rs[t >> 6] = sum; rq[t >> 6] = sq; }
    __syncthreads();
    sum = rs[0] + rs[1] + rs[2] + rs[3];
    sq  = rq[0] + rq[1] + rq[2] + rq[3];
    float mean = sum * (1.0f / 1024.0f);
    float var  = fmaxf(sq * (1.0f / 1024.0f) - mean * mean, 0.0f);
    float rstd = rsqrtf(var + 1e-5f);
#pragma unroll
    for (int j = 0; j < 4; j++) {
        int i = j * 256 + t;
        out[base + i] = (y[j] - mean) * rstd * gamma[i] + beta[i];
    }
}

// ---------------------------------------------------------------------------
extern "C" void kernel_launch(void* const* d_in, const int* in_sizes, int n_in,
                              void* d_out, int out_size, void* d_ws, size_t ws_size,
                              hipStream_t stream)
{
    const float* x     = (const float*)d_in[0];
    const float* ep    = (const float*)d_in[1];
    const float* Wq    = (const float*)d_in[2];
    const float* bq    = (const float*)d_in[3];
    const float* Wk    = (const float*)d_in[4];
    const float* bk    = (const float*)d_in[5];
    const float* Wv    = (const float*)d_in[6];
    const float* bv    = (const float*)d_in[7];
    const float* Wmu   = (const float*)d_in[8];
    const float* bmu   = (const float*)d_in[9];
    const float* Wlv   = (const float*)d_in[10];
    const float* blv   = (const float*)d_in[11];
    const float* Wg    = (const float*)d_in[12];
    const float* bg    = (const float*)d_in[13];
    const float* gamma = (const float*)d_in[14];
    const float* beta  = (const float*)d_in[15];
    float* out = (float*)d_out;

    const int M = 8192;       // B*S
    const int D = 1024;
    const int S = 2048;

    float* mu_out = out + 8388608LL;
    float* lv_out = out + 16777216LL;
    float* pg_out = out + 25165824LL;

    // Scratch overlays (d_out dead regions; ws = h only):
    //  out region: [0-3] xb | Wqb|Wkb (adjacent [2048][1024]) | Wvb
    //              [4-6] Sc (33.55MB, overwrites all of the above)
    //              [7-10] part(2KB @+0) + Wmub|Wlvb (adjacent, @+4MB)
    //              [11]  final out f32
    //  mu region: Q | Kb -> then mu_out f32
    //  lv region: VtAll [1024][8192] (16.78MB) -> then lv_out f32
    u16* xb   = (u16*)out;
    u16* Wqb  = (u16*)out + 8388608LL;     // [2048][1024]: Wq then Wk
    u16* Wkb  = (u16*)out + 9437184LL;
    u16* Wvb  = (u16*)out + 10485760LL;
    u16* Sc   = (u16*)out;
    u16* Q    = (u16*)mu_out;
    u16* Kb   = (u16*)mu_out + 8388608LL;
    u16* Vt   = (u16*)lv_out;              // VtAll [1024][8192]
    u16* h    = (u16*)d_ws;
    float* part = (float*)out;
    u16* Wmub = (u16*)out + 2097152LL;     // [2048][1024]: Wmu then Wlv
    u16* Wlvb = (u16*)out + 3145728LL;

    dim3 blk(256), blk8(512);

    // 0. Convert x, Wq, Wk, Wv to bf16.
    cvt_bf16_k<<<dim3(2048, 4), blk, 0, stream>>>(
        x,  xb,  2097152LL,
        Wq, Wqb, 262144LL,
        Wk, Wkb, 262144LL,
        Wv, Wvb, 262144LL);

    // 1. Q|K fused: C[8192,2048] = xb @ [Wq;Wk]^T, split cols -> Q, Kb
    gemm8<0, 0, 2><<<dim3(32, 8, 1), blk8, 0, stream>>>(
        xb, Wqb, bq, bk, nullptr, Q, Kb, nullptr,
        M, 2048, D, D, 1.0f, 0, 0, 0, 0);

    // 2. VtAll[1024,8192] = Wv @ x^T + bv(row)  (replaces V GEMM + transpose)
    gemm8<0, 1, 1><<<dim3(4, 32, 1), blk8, 0, stream>>>(
        Wvb, xb, bv, nullptr, nullptr, Vt, nullptr, nullptr,
        D, 8192, D, D, 1.0f, 0, 0, 0, 0);

    // 3. scores = Q @ K^T / 48 per batch -> Sc (xb/W*b now dead)
    gemm8<0, 0, 1><<<dim3(8, 8, 4), blk8, 0, stream>>>(
        Q, Kb, nullptr, nullptr, nullptr, Sc, nullptr, nullptr,
        S, S, D, D, 1.0f / 48.0f,
        (long long)S * D, (long long)S * D, (long long)S * S, 0);

    // 4. softmax in place
    softmax_k<<<dim3(8192), blk, 0, stream>>>(Sc);

    // 5. h = P @ V: A=Sc[8192][2048], B=VtAll (ldb=8192, +b*2048 k-offset)
    gemm8<0, 0, 1><<<dim3(32, 4, 1), blk8, 0, stream>>>(
        Sc, Vt, nullptr, nullptr, nullptr, h, nullptr, nullptr,
        M, D, S, 8192, 1.0f, 0, 0, 0, 2048);

    // 6. Convert Wmu, Wlv into dead Sc region (adjacent [2048][1024]).
    cvt_bf16_k<<<dim3(512, 2), blk, 0, stream>>>(
        Wmu, Wmub, 262144LL,
        Wlv, Wlvb, 262144LL,
        nullptr, nullptr, 0LL,
        nullptr, nullptr, 0LL);

    // 7. mu|lv fused: C[8192,2048] = h @ [Wmu;Wlv]^T, split -> mu_out, lv_out
    gemm8<1, 0, 2><<<dim3(32, 8, 1), blk8, 0, stream>>>(
        h, Wmub, bmu, blv, nullptr, (void*)mu_out, (void*)lv_out, nullptr,
        M, 2048, D, D, 1.0f, 0, 0, 0, 0);

    // 8. gate -> f32 p_gate
    gate_partial<<<dim3(4, 128), blk, 0, stream>>>(h, Wg, part);
    gate_final<<<dim3(1), dim3(64), 0, stream>>>(part, bg, pg_out);

    // 9. out = LN(x + relu(mu + eps*exp(0.5*logvar))) -> f32
    epilogue_k<<<dim3(8192), blk, 0, stream>>>(x, ep, mu_out, lv_out, gamma, beta, out);
}

// Round 4
// 423.904 us; speedup vs baseline: 1.1402x; 1.1402x over previous
//
#include <hip/hip_runtime.h>

typedef unsigned short u16;
typedef __attribute__((ext_vector_type(8))) short bf16x8;
typedef __attribute__((ext_vector_type(4))) float f32x4;

__device__ inline float bf2f(u16 h) {
    union { unsigned u; float f; } v; v.u = ((unsigned)h) << 16; return v.f;
}
__device__ inline u16 f2bf(float f) {
    union { float f; unsigned u; } v; v.f = f;
    unsigned r = v.u + 0x7fffu + ((v.u >> 16) & 1u);
    return (u16)(r >> 16);
}

__device__ inline void gl_lds16(const u16* g, u16* l) {
    __builtin_amdgcn_global_load_lds(
        (const __attribute__((address_space(1))) void*)g,
        (__attribute__((address_space(3))) void*)l, 16, 0, 0);
}

__device__ __forceinline__ void wgbar() {
    asm volatile("" ::: "memory");
    __builtin_amdgcn_s_barrier();
    asm volatile("" ::: "memory");
}
#define VMW(n) asm volatile("s_waitcnt vmcnt(" #n ")" ::: "memory")

// ---------------------------------------------------------------------------
// f32 -> bf16 elementwise convert, up to 4 arrays per launch.
// ---------------------------------------------------------------------------
__global__ __launch_bounds__(256) void cvt_bf16_k(
    const float* __restrict__ s0, u16* __restrict__ d0, long long n0,
    const float* __restrict__ s1, u16* __restrict__ d1, long long n1,
    const float* __restrict__ s2, u16* __restrict__ d2, long long n2,
    const float* __restrict__ s3, u16* __restrict__ d3, long long n3)
{
    int y = blockIdx.y;
    const float* s = (y == 0) ? s0 : (y == 1) ? s1 : (y == 2) ? s2 : s3;
    u16* d         = (y == 0) ? d0 : (y == 1) ? d1 : (y == 2) ? d2 : d3;
    long long n    = (y == 0) ? n0 : (y == 1) ? n1 : (y == 2) ? n2 : n3;
    for (long long i = (long long)blockIdx.x * 256 + threadIdx.x; i < n;
         i += (long long)gridDim.x * 256) {
        float4 v = ((const float4*)s)[i];
        union { u16 h[4]; unsigned long long u; } p;
        p.h[0] = f2bf(v.x); p.h[1] = f2bf(v.y);
        p.h[2] = f2bf(v.z); p.h[3] = f2bf(v.w);
        ((unsigned long long*)d)[i] = p.u;
    }
}

// ---------------------------------------------------------------------------
// 3-deep-ring pipelined GEMM: C[M,N] = (A[M,K] @ Bt[N,K]^T)*scale + bias
// BM=128, BN=256, BK=64. 512 thr = 8 waves (2M x 4N), wave tile 64x64,
// acc[4][4]. 2 phases per K-tile (ks=0/1): 16 MFMA + 8 ds_read_b128 each.
// LDS ring: 3 slots (A 16KB + B 32KB per slot = 144KB), XOR-swizzled
// (elem cg ^= row&7) with inverse-swizzled global source (both-sides rule).
// Schedule: during tile t stage tile t+2 (3+3 sites); VMW(6) at end of each
// tile confirms t+1 (issued a full tile earlier), leaves t+2 in flight.
// Counted vmcnt, never 0 mid-loop. XCD-aware block swizzle (grid%8==0).
// NSPLIT: output cols in 1024-wide segments -> C0/C1; BIASROW: bias by row.
// bofs_stride: B elem offset += (bm0>>11)*bofs_stride (PV per-batch K-offset).
// ---------------------------------------------------------------------------
#define STA(T, SL2, S)                                                        \
    { const u16* g_ = Ag + (long long)((S) * 64 + w * 8 + srow) * K           \
                      + (long long)(T) * 64 + scol;                           \
      gl_lds16(g_, &As[SL2][(S) * 4096 + w * 512]); }

#define STB(T, SL2, S)                                                        \
    { const u16* g_ = Bg + (long long)(bn0 + (S) * 64 + w * 8 + srow) * ldb   \
                      + (long long)(T) * 64 + scol;                           \
      gl_lds16(g_, &Bs[SL2][(S) * 4096 + w * 512]); }

#define G8_READS(SL, KS)                                                      \
    bf16x8 av[4], bvv[4];                                                     \
    _Pragma("unroll")                                                         \
    for (int ii = 0; ii < 4; ii++)                                            \
        av[ii] = *(const bf16x8*)&As[SL][                                     \
            ((wm * 64 + ii * 16 + lane15) * 64 + (KS) * 32 + quad * 8) ^ xr]; \
    _Pragma("unroll")                                                         \
    for (int jj = 0; jj < 4; jj++)                                            \
        bvv[jj] = *(const bf16x8*)&Bs[SL][                                    \
            ((wn * 64 + jj * 16 + lane15) * 64 + (KS) * 32 + quad * 8) ^ xr];

#define G8_MMA                                                                \
    __builtin_amdgcn_s_setprio(1);                                            \
    _Pragma("unroll")                                                         \
    for (int ii = 0; ii < 4; ii++)                                            \
        _Pragma("unroll")                                                     \
        for (int jj = 0; jj < 4; jj++)                                        \
            acc[ii][jj] = __builtin_amdgcn_mfma_f32_16x16x32_bf16(            \
                av[ii], bvv[jj], acc[ii][jj], 0, 0, 0);                       \
    __builtin_amdgcn_s_setprio(0);

template <int COUTF32, int BIASROW, int NSPLIT>
__global__ __launch_bounds__(512, 2) void gemm8(
    const u16* __restrict__ A, const u16* __restrict__ Bt,
    const float* __restrict__ bias0, const float* __restrict__ bias1,
    void* __restrict__ C0, void* __restrict__ C1,
    int M, int N, int K, int ldb, float scale,
    long long sAb, long long sBb, long long sCb, long long bofs_stride)
{
    __shared__ u16 As[3][8192];    // 3 x 128x64
    __shared__ u16 Bs[3][16384];   // 3 x 256x64

    // XCD-aware bijective block swizzle (requires gx*gy*gz % 8 == 0).
    int gx = gridDim.x, gy = gridDim.y;
    int n = gx * gy * gridDim.z;
    int flat = (blockIdx.z * gy + blockIdx.y) * gx + blockIdx.x;
    int L = (flat & 7) * (n >> 3) + (flat >> 3);
    int bz = L / (gx * gy);
    int rr = L - bz * gx * gy;
    int by = rr / gx, bx = rr - (rr / gx) * gx;

    int bm0 = bx * 128;
    int bn0 = by * 256;
    int b   = bz;
    int tid = threadIdx.x;
    int w = tid >> 6, l = tid & 63;
    int wm = w >> 2;             // M half (64 rows)
    int wn = w & 3;              // N quarter (64 cols)
    int lane15 = l & 15, quad = l >> 4;
    int xr = (l & 7) << 3;       // read-side swizzle (elems); row&7 == l&7

    // staging lane geometry: 8 lanes/row, inverse-swizzled source col-group
    int srow = l >> 3;
    int scol = ((l & 7) ^ srow) * 8;

    const u16* Ag = A  + (long long)b * sAb + (long long)bm0 * K;
    const u16* Bg = Bt + (long long)b * sBb + (long long)(bm0 >> 11) * bofs_stride;

    f32x4 acc[4][4];
#pragma unroll
    for (int i = 0; i < 4; i++)
#pragma unroll
        for (int j = 0; j < 4; j++) acc[i][j] = (f32x4)(0.0f);

    int NT = K >> 6;

    // Prologue: stage tiles 0 and 1 (6 sites each); confirm t0, t1 in flight.
    STA(0, 0, 0); STA(0, 0, 1);
    STB(0, 0, 0); STB(0, 0, 1); STB(0, 0, 2); STB(0, 0, 3);
    STA(1, 1, 0); STA(1, 1, 1);
    STB(1, 1, 0); STB(1, 1, 1); STB(1, 1, 2); STB(1, 1, 3);
    VMW(6);
    wgbar();

    int sl = 0, sl2 = 2;
    for (int t = 0; t < NT; ++t) {
        bool pf = (t + 2 < NT);
        int t2 = t + 2;
        // phase A (ks=0): 8 ds_read + 3 stage sites, bar, 16 MFMA, bar
        {
            G8_READS(sl, 0);
            if (pf) { STA(t2, sl2, 0); STA(t2, sl2, 1); STB(t2, sl2, 0); }
            wgbar();
            G8_MMA;
            wgbar();
        }
        // phase B (ks=1): 8 ds_read + 3 stage sites, VMW(6) confirms t+1
        {
            G8_READS(sl, 1);
            if (pf) {
                STB(t2, sl2, 1); STB(t2, sl2, 2); STB(t2, sl2, 3);
                VMW(6);
            } else {
                VMW(0);
            }
            wgbar();
            G8_MMA;
            wgbar();
        }
        sl  = (sl  == 2) ? 0 : sl + 1;
        sl2 = (sl2 == 2) ? 0 : sl2 + 1;
    }

    // Epilogue: C/D layout col = lane15 (frag jj), row = quad*4 + r (frag ii)
    float rowb_[4][4];
    if (BIASROW) {
#pragma unroll
        for (int i = 0; i < 4; i++)
#pragma unroll
            for (int r = 0; r < 4; r++)
                rowb_[i][r] = bias0[bm0 + wm * 64 + i * 16 + quad * 4 + r];
    }
#pragma unroll
    for (int jj = 0; jj < 4; jj++) {
        int col = bn0 + wn * 64 + jj * 16 + lane15;
        int seg, cl, cstride;
        if (NSPLIT == 1) { seg = 0; cl = col; cstride = N; }
        else             { seg = col >> 10; cl = col & 1023; cstride = 1024; }
        const float* bp = (seg == 0) ? bias0 : bias1;
        void* cb = (seg == 0) ? C0 : C1;
        u16*   c16 = (u16*)cb   + (long long)b * sCb;
        float* c32 = (float*)cb + (long long)b * sCb;
        float bvc = (!BIASROW && bp) ? bp[cl] : 0.0f;
#pragma unroll
        for (int i = 0; i < 4; i++) {
            int row0 = bm0 + wm * 64 + i * 16 + quad * 4;
#pragma unroll
            for (int r = 0; r < 4; r++) {
                float v = acc[i][jj][r] * scale + (BIASROW ? rowb_[i][r] : bvc);
                if (COUTF32) c32[(long long)(row0 + r) * cstride + cl] = v;
                else         c16[(long long)(row0 + r) * cstride + cl] = f2bf(v);
            }
        }
    }
}

// ---------------------------------------------------------------------------
// Row softmax in-place: 8192 rows of 2048 bf16
// ---------------------------------------------------------------------------
__global__ __launch_bounds__(256) void softmax_k(u16* __restrict__ Sc)
{
    long long row = blockIdx.x;
    u16* s = Sc + row * 2048;
    int t = threadIdx.x;

    uint4 raw = *(const uint4*)(s + t * 8);
    const u16* rp = (const u16*)&raw;
    float v[8];
    float mx = -3.4e38f;
#pragma unroll
    for (int j = 0; j < 8; j++) { v[j] = bf2f(rp[j]); mx = fmaxf(mx, v[j]); }
#pragma unroll
    for (int o = 32; o > 0; o >>= 1) mx = fmaxf(mx, __shfl_xor(mx, o));
    __shared__ float redm[4];
    if ((t & 63) == 0) redm[t >> 6] = mx;
    __syncthreads();
    mx = fmaxf(fmaxf(redm[0], redm[1]), fmaxf(redm[2], redm[3]));

    float sum = 0.0f;
#pragma unroll
    for (int j = 0; j < 8; j++) { v[j] = __expf(v[j] - mx); sum += v[j]; }
#pragma unroll
    for (int o = 32; o > 0; o >>= 1) sum += __shfl_xor(sum, o);
    __shared__ float reds[4];
    if ((t & 63) == 0) reds[t >> 6] = sum;
    __syncthreads();
    sum = reds[0] + reds[1] + reds[2] + reds[3];

    float inv = 1.0f / sum;
    u16 o8[8];
#pragma unroll
    for (int j = 0; j < 8; j++) o8[j] = f2bf(v[j] * inv);
    *(uint4*)(s + t * 8) = *(const uint4*)o8;
}

// ---------------------------------------------------------------------------
// Gate partial: grid (B, 128). Each block: 16 rows of h[b], bf16x8 loads.
// ---------------------------------------------------------------------------
__global__ __launch_bounds__(256) void gate_partial(const u16* __restrict__ h,
                                                    const float* __restrict__ Wg,
                                                    float* __restrict__ part)
{
    int b = blockIdx.x, c = blockIdx.y;
    int t = threadIdx.x;
    int tx = t & 127;
    int ty = t >> 7;
    int d0 = tx * 8;
    const u16* hb = h + (long long)b * 2048 * 1024 + (long long)c * 16 * 1024;

    float wg[8];
#pragma unroll
    for (int j = 0; j < 8; j++) wg[j] = Wg[d0 + j];

    float acc = 0.0f;
    for (int s = ty; s < 16; s += 2) {
        bf16x8 hv = *(const bf16x8*)&hb[(long long)s * 1024 + d0];
        const u16* hp = (const u16*)&hv;
#pragma unroll
        for (int j = 0; j < 8; j++) acc += bf2f(hp[j]) * wg[j];
    }
#pragma unroll
    for (int o = 32; o > 0; o >>= 1) acc += __shfl_xor(acc, o);
    __shared__ float red[4];
    if ((t & 63) == 0) red[t >> 6] = acc;
    __syncthreads();
    if (t == 0) part[b * 128 + c] = red[0] + red[1] + red[2] + red[3];
}

__global__ void gate_final(const float* __restrict__ part,
                           const float* __restrict__ bg, float* __restrict__ outp)
{
    int t = threadIdx.x;
    if (t < 4) {
        float s = 0.0f;
        for (int c = 0; c < 128; c++) s += part[t * 128 + c];
        float v = s * (1.0f / 2048.0f) + bg[0];
        outp[t] = 1.0f / (1.0f + __expf(-v));
    }
}

// ---------------------------------------------------------------------------
// Epilogue: z = relu(mu + eps*exp(0.5*logvar)); out = LN(x+z)*gamma+beta
// ---------------------------------------------------------------------------
__global__ __launch_bounds__(256) void epilogue_k(
    const float* __restrict__ x, const float* __restrict__ ep,
    const float* __restrict__ mu, const float* __restrict__ lv,
    const float* __restrict__ gamma, const float* __restrict__ beta,
    float* __restrict__ out)
{
    long long base = (long long)blockIdx.x * 1024;
    int t = threadIdx.x;
    float y[4];
    float sum = 0.0f, sq = 0.0f;
#pragma unroll
    for (int j = 0; j < 4; j++) {
        int i = j * 256 + t;
        float xv = x[base + i];
        float ev = ep[base + i];
        float m  = mu[base + i];
        float sd = __expf(0.5f * lv[base + i]);
        float z  = fmaxf(m + ev * sd, 0.0f);
        float yy = xv + z;
        y[j] = yy; sum += yy; sq += yy * yy;
    }
#pragma unroll
    for (int o = 32; o > 0; o >>= 1) { sum += __shfl_xor(sum, o); sq += __shfl_xor(sq, o); }
    __shared__ float rs[4], rq[4];
    if ((t & 63) == 0) { rs[t >> 6] = sum; rq[t >> 6] = sq; }
    __syncthreads();
    sum = rs[0] + rs[1] + rs[2] + rs[3];
    sq  = rq[0] + rq[1] + rq[2] + rq[3];
    float mean = sum * (1.0f / 1024.0f);
    float var  = fmaxf(sq * (1.0f / 1024.0f) - mean * mean, 0.0f);
    float rstd = rsqrtf(var + 1e-5f);
#pragma unroll
    for (int j = 0; j < 4; j++) {
        int i = j * 256 + t;
        out[base + i] = (y[j] - mean) * rstd * gamma[i] + beta[i];
    }
}

// ---------------------------------------------------------------------------
extern "C" void kernel_launch(void* const* d_in, const int* in_sizes, int n_in,
                              void* d_out, int out_size, void* d_ws, size_t ws_size,
                              hipStream_t stream)
{
    const float* x     = (const float*)d_in[0];
    const float* ep    = (const float*)d_in[1];
    const float* Wq    = (const float*)d_in[2];
    const float* bq    = (const float*)d_in[3];
    const float* Wk    = (const float*)d_in[4];
    const float* bk    = (const float*)d_in[5];
    const float* Wv    = (const float*)d_in[6];
    const float* bv    = (const float*)d_in[7];
    const float* Wmu   = (const float*)d_in[8];
    const float* bmu   = (const float*)d_in[9];
    const float* Wlv   = (const float*)d_in[10];
    const float* blv   = (const float*)d_in[11];
    const float* Wg    = (const float*)d_in[12];
    const float* bg    = (const float*)d_in[13];
    const float* gamma = (const float*)d_in[14];
    const float* beta  = (const float*)d_in[15];
    float* out = (float*)d_out;

    const int M = 8192;       // B*S
    const int D = 1024;
    const int S = 2048;

    float* mu_out = out + 8388608LL;
    float* lv_out = out + 16777216LL;
    float* pg_out = out + 25165824LL;

    // Scratch overlays (d_out dead regions; ws = h only):
    //  out region: [0-2] xb | Wqb|Wkb (adjacent) | Wvb
    //              [3-5] Sc (33.55MB, overwrites all of the above)
    //              [6-8] part(2KB @+0) + Wmub|Wlvb (adjacent, @+4MB)
    //              [9]   final out f32
    //  mu region: Q | Kb -> then mu_out f32
    //  lv region: VtAll [1024][8192] -> then lv_out f32
    u16* xb   = (u16*)out;
    u16* Wqb  = (u16*)out + 8388608LL;     // [2048][1024]: Wq then Wk
    u16* Wkb  = (u16*)out + 9437184LL;
    u16* Wvb  = (u16*)out + 10485760LL;
    u16* Sc   = (u16*)out;
    u16* Q    = (u16*)mu_out;
    u16* Kb   = (u16*)mu_out + 8388608LL;
    u16* Vt   = (u16*)lv_out;              // VtAll [1024][8192]
    u16* h    = (u16*)d_ws;
    float* part = (float*)out;
    u16* Wmub = (u16*)out + 2097152LL;     // [2048][1024]: Wmu then Wlv
    u16* Wlvb = (u16*)out + 3145728LL;

    dim3 blk(256), blk8(512);

    // 0. Convert x, Wq, Wk, Wv to bf16.
    cvt_bf16_k<<<dim3(2048, 4), blk, 0, stream>>>(
        x,  xb,  2097152LL,
        Wq, Wqb, 262144LL,
        Wk, Wkb, 262144LL,
        Wv, Wvb, 262144LL);

    // 1. Q|K fused: C[8192,2048] = xb @ [Wq;Wk]^T, split cols -> Q, Kb
    gemm8<0, 0, 2><<<dim3(64, 8, 1), blk8, 0, stream>>>(
        xb, Wqb, bq, bk, Q, Kb,
        M, 2048, D, D, 1.0f, 0, 0, 0, 0);

    // 2. VtAll[1024,8192] = Wv @ x^T + bv(row)  (V GEMM + transpose in one)
    gemm8<0, 1, 1><<<dim3(8, 32, 1), blk8, 0, stream>>>(
        Wvb, xb, bv, nullptr, Vt, nullptr,
        D, 8192, D, D, 1.0f, 0, 0, 0, 0);

    // 3. scores = Q @ K^T / 48 per batch -> Sc (xb/W*b now dead)
    gemm8<0, 0, 1><<<dim3(16, 8, 4), blk8, 0, stream>>>(
        Q, Kb, nullptr, nullptr, Sc, nullptr,
        S, S, D, D, 1.0f / 48.0f,
        (long long)S * D, (long long)S * D, (long long)S * S, 0);

    // 4. softmax in place
    softmax_k<<<dim3(8192), blk, 0, stream>>>(Sc);

    // 5. h = P @ V: A=Sc[8192][2048], B=VtAll (ldb=8192, +b*2048 K-offset)
    gemm8<0, 0, 1><<<dim3(64, 4, 1), blk8, 0, stream>>>(
        Sc, Vt, nullptr, nullptr, h, nullptr,
        M, D, S, 8192, 1.0f, 0, 0, 0, 2048);

    // 6. Convert Wmu, Wlv into dead Sc region (adjacent [2048][1024]).
    cvt_bf16_k<<<dim3(512, 2), blk, 0, stream>>>(
        Wmu, Wmub, 262144LL,
        Wlv, Wlvb, 262144LL,
        nullptr, nullptr, 0LL,
        nullptr, nullptr, 0LL);

    // 7. mu|lv fused: C[8192,2048] = h @ [Wmu;Wlv]^T, split -> mu_out, lv_out
    gemm8<1, 0, 2><<<dim3(64, 8, 1), blk8, 0, stream>>>(
        h, Wmub, bmu, blv, (void*)mu_out, (void*)lv_out,
        M, 2048, D, D, 1.0f, 0, 0, 0, 0);

    // 8. gate -> f32 p_gate
    gate_partial<<<dim3(4, 128), blk, 0, stream>>>(h, Wg, part);
    gate_final<<<dim3(1), dim3(64), 0, stream>>>(part, bg, pg_out);

    // 9. out = LN(x + relu(mu + eps*exp(0.5*logvar))) -> f32
    epilogue_k<<<dim3(8192), blk, 0, stream>>>(x, ep, mu_out, lv_out, gamma, beta, out);
}